// Round 1
// baseline (360.334 us; speedup 1.0000x reference)
//
#include <hip/hip_runtime.h>
#include <hip/hip_bf16.h>

#define DM    1024
#define NH    16
#define DKH   64
#define BB    4
#define SS    2048
#define MROWS (BB*SS)     // 8192
#define QKVN  (3*DM)      // 3072

typedef __attribute__((ext_vector_type(8))) __bf16 bf16x8;
typedef __attribute__((ext_vector_type(4))) float f32x4;
typedef __attribute__((ext_vector_type(4))) unsigned short u16x4;

__device__ __forceinline__ void gload_lds16(const void* g, void* l) {
  __builtin_amdgcn_global_load_lds((const __attribute__((address_space(1))) void*)g,
                                   (__attribute__((address_space(3))) void*)l, 16, 0, 0);
}

__device__ __forceinline__ unsigned short f2bf(float f) {
  __hip_bfloat16 h = __float2bfloat16(f);
  unsigned short u;
  __builtin_memcpy(&u, &h, 2);
  return u;
}

// ---------------- conversion kernels ----------------

__global__ __launch_bounds__(256) void cvt_bf16_kernel(const float* __restrict__ in,
                                                       unsigned short* __restrict__ out, int n4) {
  int i = blockIdx.x * 256 + threadIdx.x;
  if (i >= n4) return;
  float4 v = reinterpret_cast<const float4*>(in)[i];
  u16x4 o = { f2bf(v.x), f2bf(v.y), f2bf(v.z), f2bf(v.w) };
  reinterpret_cast<u16x4*>(out)[i] = o;
}

__global__ __launch_bounds__(256) void transpose_cvt_kernel(const float* __restrict__ W,
                                                            unsigned short* __restrict__ WT) {
  __shared__ float t[32][33];
  int tx = threadIdx.x & 31, ty = threadIdx.x >> 5;
  int bx = blockIdx.x * 32, by = blockIdx.y * 32;
#pragma unroll
  for (int i = 0; i < 32; i += 8)
    t[ty + i][tx] = W[(long)(by + ty + i) * DM + bx + tx];
  __syncthreads();
#pragma unroll
  for (int i = 0; i < 32; i += 8)
    WT[(long)(bx + ty + i) * DM + by + tx] = f2bf(t[tx][ty + i]);
}

__global__ void concat_bias_kernel(const float* __restrict__ a, const float* __restrict__ b,
                                   const float* __restrict__ c, float* __restrict__ out) {
  int i = blockIdx.x * 256 + threadIdx.x;
  if (i >= QKVN) return;
  out[i] = (i < DM) ? a[i] : (i < 2 * DM) ? b[i - DM] : c[i - 2 * DM];
}

// ---------------- GEMM: C[M][N] = A[M][K] * BT[N][K]^T + bias (m97 structure) ----------------

__device__ __forceinline__ void store_out(float* p, float v) { *p = v; }
__device__ __forceinline__ void store_out(unsigned short* p, float v) { *p = f2bf(v); }

template <typename OutT, bool QKV_SCALE>
__global__ __launch_bounds__(256) void gemm_bt_kernel(
    const unsigned short* __restrict__ A,   // [M][K] bf16 bits
    const unsigned short* __restrict__ BT,  // [N][K] bf16 bits
    const float* __restrict__ bias,         // [N]
    OutT* __restrict__ C, int M, int N, int K) {
  __shared__ unsigned short As[128 * 32];
  __shared__ unsigned short Bs[128 * 32];
  const int tid = threadIdx.x;
  const int lane = tid & 63;
  const int lr = lane & 15, lg = lane >> 4;
  const int wv = tid >> 6, wm = wv >> 1, wn = wv & 1;
  const long bm = blockIdx.x, bn = blockIdx.y;

  const unsigned short* Ag = A + bm * 128 * K;
  const unsigned short* Bg = BT + bn * 128 * K;

  f32x4 acc[4][4];
#pragma unroll
  for (int i = 0; i < 4; ++i)
#pragma unroll
    for (int j = 0; j < 4; ++j) acc[i][j] = (f32x4){0.f, 0.f, 0.f, 0.f};

  for (int kt = 0; kt < K; kt += 32) {
#pragma unroll
    for (int it = 0; it < 2; ++it) {
      const int e = it * 2048 + tid * 8;
      const int row = e >> 5, col = e & 31;
      gload_lds16(Ag + (long)row * K + kt + col, As + e);
      gload_lds16(Bg + (long)row * K + kt + col, Bs + e);
    }
    __syncthreads();
    bf16x8 af[4], bfr[4];
#pragma unroll
    for (int mi = 0; mi < 4; ++mi)
      af[mi] = *reinterpret_cast<const bf16x8*>(As + (wm * 64 + mi * 16 + lr) * 32 + lg * 8);
#pragma unroll
    for (int ni = 0; ni < 4; ++ni)
      bfr[ni] = *reinterpret_cast<const bf16x8*>(Bs + (wn * 64 + ni * 16 + lr) * 32 + lg * 8);
#pragma unroll
    for (int mi = 0; mi < 4; ++mi)
#pragma unroll
      for (int ni = 0; ni < 4; ++ni)
        acc[mi][ni] = __builtin_amdgcn_mfma_f32_16x16x32_bf16(af[mi], bfr[ni], acc[mi][ni], 0, 0, 0);
    __syncthreads();
  }

#pragma unroll
  for (int ni = 0; ni < 4; ++ni) {
    const int col = (int)bn * 128 + wn * 64 + ni * 16 + lr;
    const float bv = bias[col];
    // fold softmax scale (1/sqrt(dk)) * log2(e) into Q so attention can use exp2 natively
    const float sc = (QKV_SCALE && col < DM) ? (0.125f * 1.44269504088896340736f) : 1.0f;
#pragma unroll
    for (int mi = 0; mi < 4; ++mi) {
      const long row0 = bm * 128 + wm * 64 + mi * 16 + lg * 4;
#pragma unroll
      for (int r = 0; r < 4; ++r) {
        float v = (acc[mi][ni][r] + bv) * sc;
        store_out(&C[(row0 + r) * N + col], v);
      }
    }
  }
}

// ---------------- flash attention: block = (b,h) x 64 q-rows, 4 waves x 16 rows ----------------

__global__ __launch_bounds__(256) void attn_kernel(
    const unsigned short* __restrict__ QKV,  // [8192][3072] bf16: cols 0..1023=Q(prescaled),1024..2047=K,2048..=V
    unsigned short* __restrict__ AO) {       // [8192][1024] bf16, [b][s][h][dk]
  __shared__ unsigned short Ks[64 * 64];     // K tile, row-major [key][d], XOR-swizzled 16B blocks
  __shared__ unsigned short Vt[64 * 64];     // V^T tile [d][key], XOR-swizzled
  __shared__ unsigned short Pl[4][16 * 64];  // per-wave P [q][key], XOR-swizzled

  const int tid = threadIdx.x;
  const int lane = tid & 63;
  const int wv = tid >> 6;
  const int lr = lane & 15, lg = lane >> 4;

  const int qt = blockIdx.x;  // 0..31
  const int bh = blockIdx.y;  // 0..63
  const int b = bh >> 4, h = bh & 15;

  const unsigned short* Qp = QKV + (long)b * SS * QKVN + h * DKH;
  const unsigned short* Kp = Qp + DM;
  const unsigned short* Vp = Qp + 2 * DM;

  // Q fragments held in registers: A-frag row = lr, k = lg*8..+8 (two 32-wide k-subtiles)
  bf16x8 qf[2];
  {
    const unsigned short* qrow = Qp + (long)(qt * 64 + wv * 16 + lr) * QKVN;
    qf[0] = *reinterpret_cast<const bf16x8*>(qrow + lg * 8);
    qf[1] = *reinterpret_cast<const bf16x8*>(qrow + 32 + lg * 8);
  }

  f32x4 acc_o[4];
#pragma unroll
  for (int i = 0; i < 4; ++i) acc_o[i] = (f32x4){0.f, 0.f, 0.f, 0.f};
  float m_run[4], l_run[4];  // per q-row (q = lg*4 + r), base-2 domain
#pragma unroll
  for (int r = 0; r < 4; ++r) { m_run[r] = -1e30f; l_run[r] = 0.f; }

  unsigned short* Pw = &Pl[wv][0];

  for (int kt = 0; kt < SS / 64; ++kt) {
    // ---- stage K via global_load_lds; source pre-swizzled so swizzled READ is correct ----
#pragma unroll
    for (int it = 0; it < 2; ++it) {
      const int s = it * 256 + tid;        // 16B-block index 0..511
      const int key = s >> 3, blk = s & 7;
      const int blkL = blk ^ (key & 7);    // logical 16B block of this row
      gload_lds16(Kp + (long)(kt * 64 + key) * QKVN + blkL * 8, Ks + s * 8);
    }
    // ---- stage V transposed (reg path), XOR swizzle f(d) = (d&7)^((d>>3)&7) ----
#pragma unroll
    for (int it = 0; it < 2; ++it) {
      const int e = it * 2048 + tid * 8;
      const int key = e >> 6, d0 = e & 63;
      union { bf16x8 v; unsigned short u[8]; } tv;
      tv.v = *reinterpret_cast<const bf16x8*>(Vp + (long)(kt * 64 + key) * QKVN + d0);
#pragma unroll
      for (int i = 0; i < 8; ++i) {
        const int d = d0 + i;
        const int blk = ((key >> 3) ^ (d & 7) ^ ((d >> 3) & 7)) & 7;
        Vt[d * 64 + (blk << 3) + (key & 7)] = tv.u[i];
      }
    }
    __syncthreads();

    // ---- QK^T: D[q][key], q = lg*4+r, key = ktile*16+lr ----
    f32x4 s4[4];
#pragma unroll
    for (int i = 0; i < 4; ++i) s4[i] = (f32x4){0.f, 0.f, 0.f, 0.f};
#pragma unroll
    for (int ktile = 0; ktile < 4; ++ktile) {
      const int key = ktile * 16 + lr;
#pragma unroll
      for (int ks = 0; ks < 2; ++ks) {
        const int blk = ((ks * 4 + lg) ^ (key & 7)) & 7;
        bf16x8 kf = *reinterpret_cast<const bf16x8*>(Ks + key * 64 + (blk << 3));
        s4[ktile] = __builtin_amdgcn_mfma_f32_16x16x32_bf16(qf[ks], kf, s4[ktile], 0, 0, 0);
      }
    }

    // ---- online softmax (scores already in log2 units via folded Q scale) ----
    float mloc[4];
#pragma unroll
    for (int r = 0; r < 4; ++r)
      mloc[r] = fmaxf(fmaxf(s4[0][r], s4[1][r]), fmaxf(s4[2][r], s4[3][r]));
#pragma unroll
    for (int x = 1; x <= 8; x <<= 1)
#pragma unroll
      for (int r = 0; r < 4; ++r)
        mloc[r] = fmaxf(mloc[r], __shfl_xor(mloc[r], x));
    float scl[4], ssum[4];
#pragma unroll
    for (int r = 0; r < 4; ++r) {
      float mn = fmaxf(m_run[r], mloc[r]);
      scl[r] = __builtin_amdgcn_exp2f(m_run[r] - mn);
      m_run[r] = mn;
      ssum[r] = 0.f;
    }
#pragma unroll
    for (int ktile = 0; ktile < 4; ++ktile)
#pragma unroll
      for (int r = 0; r < 4; ++r) {
        float p = __builtin_amdgcn_exp2f(s4[ktile][r] - m_run[r]);
        s4[ktile][r] = p;
        ssum[r] += p;
      }
#pragma unroll
    for (int x = 1; x <= 8; x <<= 1)
#pragma unroll
      for (int r = 0; r < 4; ++r)
        ssum[r] += __shfl_xor(ssum[r], x);
#pragma unroll
    for (int r = 0; r < 4; ++r)
      l_run[r] = l_run[r] * scl[r] + ssum[r];
#pragma unroll
    for (int ni = 0; ni < 4; ++ni)
#pragma unroll
      for (int r = 0; r < 4; ++r)
        acc_o[ni][r] *= scl[r];

    // ---- write P to per-wave LDS (bf16, swizzled) ----
#pragma unroll
    for (int ktile = 0; ktile < 4; ++ktile)
#pragma unroll
      for (int r = 0; r < 4; ++r) {
        const int q = lg * 4 + r;
        const int key = ktile * 16 + lr;
        Pw[q * 64 + ((((key >> 3) ^ (q & 7)) & 7) << 3) + (key & 7)] = f2bf(s4[ktile][r]);
      }

    // ---- PV: acc_o[ni] += P[16x64] * V[64x(ni*16..)] ----
#pragma unroll
    for (int ks = 0; ks < 2; ++ks) {
      const int pblk = ((ks * 4 + lg) ^ (lr & 7)) & 7;
      bf16x8 pf = *reinterpret_cast<const bf16x8*>(Pw + lr * 64 + (pblk << 3));
#pragma unroll
      for (int ni = 0; ni < 4; ++ni) {
        const int d = ni * 16 + lr;
        const int vblk = ((ks * 4 + lg) ^ (d & 7) ^ ((d >> 3) & 7)) & 7;
        bf16x8 vf = *reinterpret_cast<const bf16x8*>(Vt + d * 64 + (vblk << 3));
        acc_o[ni] = __builtin_amdgcn_mfma_f32_16x16x32_bf16(pf, vf, acc_o[ni], 0, 0, 0);
      }
    }
    __syncthreads();
  }

  // ---- epilogue: normalize and store bf16 [b][s][h][dk] ----
  float inv[4];
#pragma unroll
  for (int r = 0; r < 4; ++r) inv[r] = 1.0f / l_run[r];
#pragma unroll
  for (int ni = 0; ni < 4; ++ni)
#pragma unroll
    for (int r = 0; r < 4; ++r) {
      const long row = (long)b * SS + qt * 64 + wv * 16 + lg * 4 + r;
      const int col = h * DKH + ni * 16 + lr;
      AO[row * DM + col] = f2bf(acc_o[ni][r] * inv[r]);
    }
}

// ---------------- launch ----------------

extern "C" void kernel_launch(void* const* d_in, const int* in_sizes, int n_in,
                              void* d_out, int out_size, void* d_ws, size_t ws_size,
                              hipStream_t stream) {
  const float* x  = (const float*)d_in[0];
  const float* Wq = (const float*)d_in[1];
  const float* bq = (const float*)d_in[2];
  const float* Wk = (const float*)d_in[3];
  const float* bk = (const float*)d_in[4];
  const float* Wv = (const float*)d_in[5];
  const float* bv = (const float*)d_in[6];
  const float* Wo = (const float*)d_in[7];
  const float* bo = (const float*)d_in[8];
  float* out = (float*)d_out;

  char* ws = (char*)d_ws;
  size_t off = 0;
  auto alloc = [&](size_t bytes) {
    void* p = ws + off;
    off += (bytes + 255) & ~(size_t)255;
    return p;
  };
  unsigned short* Xb   = (unsigned short*)alloc((size_t)MROWS * DM * 2);   // x in bf16
  unsigned short* WTq  = (unsigned short*)alloc((size_t)3 * DM * DM * 2);  // WqT,WkT,WvT stacked [3072][1024]
  unsigned short* WTo  = (unsigned short*)alloc((size_t)DM * DM * 2);      // WoT [1024][1024]
  float*          bqkv = (float*)alloc((size_t)QKVN * 4);
  unsigned short* QKVb = (unsigned short*)alloc((size_t)MROWS * QKVN * 2); // fused QKV output
  unsigned short* AOb  = (unsigned short*)alloc((size_t)MROWS * DM * 2);   // attention output

  cvt_bf16_kernel<<<(MROWS * DM / 4 + 255) / 256, 256, 0, stream>>>(x, Xb, MROWS * DM / 4);
  transpose_cvt_kernel<<<dim3(32, 32), 256, 0, stream>>>(Wq, WTq);
  transpose_cvt_kernel<<<dim3(32, 32), 256, 0, stream>>>(Wk, WTq + DM * DM);
  transpose_cvt_kernel<<<dim3(32, 32), 256, 0, stream>>>(Wv, WTq + 2 * DM * DM);
  transpose_cvt_kernel<<<dim3(32, 32), 256, 0, stream>>>(Wo, WTo);
  concat_bias_kernel<<<(QKVN + 255) / 256, 256, 0, stream>>>(bq, bk, bv, bqkv);

  // fused QKV projection: [8192][3072] = Xb [8192][1024] @ WTq^T, Q columns pre-scaled
  gemm_bt_kernel<unsigned short, true><<<dim3(MROWS / 128, QKVN / 128), 256, 0, stream>>>(
      Xb, WTq, bqkv, QKVb, MROWS, QKVN, DM);

  attn_kernel<<<dim3(SS / 64, BB * NH), 256, 0, stream>>>(QKVb, AOb);

  // output projection -> fp32 d_out
  gemm_bt_kernel<float, false><<<dim3(MROWS / 128, DM / 128), 256, 0, stream>>>(
      AOb, WTo, bo, out, MROWS, DM, DM);
}

// Round 2
// 259.258 us; speedup vs baseline: 1.3899x; 1.3899x over previous
//
#include <hip/hip_runtime.h>
#include <hip/hip_bf16.h>

#define DM    1024
#define NH    16
#define DKH   64
#define BB    4
#define SS    2048
#define MROWS (BB*SS)     // 8192
#define NQK   2048        // Q,K fused projection width

typedef __attribute__((ext_vector_type(8))) __bf16 bf16x8;
typedef __attribute__((ext_vector_type(4))) float f32x4;
typedef __attribute__((ext_vector_type(4))) unsigned short u16x4;

__device__ __forceinline__ void gload_lds16(const void* g, void* l) {
  __builtin_amdgcn_global_load_lds((const __attribute__((address_space(1))) void*)g,
                                   (__attribute__((address_space(3))) void*)l, 16, 0, 0);
}

__device__ __forceinline__ unsigned short f2bf(float f) {
  __hip_bfloat16 h = __float2bfloat16(f);
  unsigned short u;
  __builtin_memcpy(&u, &h, 2);
  return u;
}

// ---------------- conversion kernels ----------------

__global__ __launch_bounds__(256) void cvt_bf16_kernel(const float* __restrict__ in,
                                                       unsigned short* __restrict__ out, int n4) {
  int i = blockIdx.x * 256 + threadIdx.x;
  if (i >= n4) return;
  float4 v = reinterpret_cast<const float4*>(in)[i];
  u16x4 o = { f2bf(v.x), f2bf(v.y), f2bf(v.z), f2bf(v.w) };
  reinterpret_cast<u16x4*>(out)[i] = o;
}

__global__ __launch_bounds__(256) void transpose_cvt_kernel(const float* __restrict__ W,
                                                            unsigned short* __restrict__ WT) {
  __shared__ float t[32][33];
  int tx = threadIdx.x & 31, ty = threadIdx.x >> 5;
  int bx = blockIdx.x * 32, by = blockIdx.y * 32;
#pragma unroll
  for (int i = 0; i < 32; i += 8)
    t[ty + i][tx] = W[(long)(by + ty + i) * DM + bx + tx];
  __syncthreads();
#pragma unroll
  for (int i = 0; i < 32; i += 8)
    WT[(long)(bx + ty + i) * DM + by + tx] = f2bf(t[tx][ty + i]);
}

__global__ void concat2_bias_kernel(const float* __restrict__ a, const float* __restrict__ b,
                                    float* __restrict__ out) {
  int i = blockIdx.x * 256 + threadIdx.x;
  if (i >= NQK) return;
  out[i] = (i < DM) ? a[i] : b[i - DM];
}

// ---------------- GEMM: C[M][N] = A[M][K] * BT[N][K]^T + bias (m97 structure) ----------------

__device__ __forceinline__ void store_out(float* p, float v) { *p = v; }
__device__ __forceinline__ void store_out(unsigned short* p, float v) { *p = f2bf(v); }

template <typename OutT, bool Q_SCALE, bool BIAS_ROW>
__global__ __launch_bounds__(256) void gemm_bt_kernel(
    const unsigned short* __restrict__ A,   // [M][K] bf16 bits
    const unsigned short* __restrict__ BT,  // [N][K] bf16 bits
    const float* __restrict__ bias,         // [N] (or [M] if BIAS_ROW)
    OutT* __restrict__ C, int M, int N, int K) {
  __shared__ unsigned short As[128 * 32];
  __shared__ unsigned short Bs[128 * 32];
  const int tid = threadIdx.x;
  const int lane = tid & 63;
  const int lr = lane & 15, lg = lane >> 4;
  const int wv = tid >> 6, wm = wv >> 1, wn = wv & 1;
  const long bm = blockIdx.x, bn = blockIdx.y;

  const unsigned short* Ag = A + bm * 128 * K;
  const unsigned short* Bg = BT + bn * 128 * K;

  f32x4 acc[4][4];
#pragma unroll
  for (int i = 0; i < 4; ++i)
#pragma unroll
    for (int j = 0; j < 4; ++j) acc[i][j] = (f32x4){0.f, 0.f, 0.f, 0.f};

  for (int kt = 0; kt < K; kt += 32) {
#pragma unroll
    for (int it = 0; it < 2; ++it) {
      const int e = it * 2048 + tid * 8;
      const int row = e >> 5, col = e & 31;
      gload_lds16(Ag + (long)row * K + kt + col, As + e);
      gload_lds16(Bg + (long)row * K + kt + col, Bs + e);
    }
    __syncthreads();
    bf16x8 af[4], bfr[4];
#pragma unroll
    for (int mi = 0; mi < 4; ++mi)
      af[mi] = *reinterpret_cast<const bf16x8*>(As + (wm * 64 + mi * 16 + lr) * 32 + lg * 8);
#pragma unroll
    for (int ni = 0; ni < 4; ++ni)
      bfr[ni] = *reinterpret_cast<const bf16x8*>(Bs + (wn * 64 + ni * 16 + lr) * 32 + lg * 8);
#pragma unroll
    for (int mi = 0; mi < 4; ++mi)
#pragma unroll
      for (int ni = 0; ni < 4; ++ni)
        acc[mi][ni] = __builtin_amdgcn_mfma_f32_16x16x32_bf16(af[mi], bfr[ni], acc[mi][ni], 0, 0, 0);
    __syncthreads();
  }

#pragma unroll
  for (int ni = 0; ni < 4; ++ni) {
    const int col = (int)bn * 128 + wn * 64 + ni * 16 + lr;
    const float bc = BIAS_ROW ? 0.f : bias[col];
    // fold softmax scale (1/sqrt(dk)) * log2(e) into Q so attention uses exp2 natively
    const float sc = (Q_SCALE && col < DM) ? (0.125f * 1.44269504088896340736f) : 1.0f;
#pragma unroll
    for (int mi = 0; mi < 4; ++mi) {
      const long row0 = bm * 128 + wm * 64 + mi * 16 + lg * 4;
#pragma unroll
      for (int r = 0; r < 4; ++r) {
        const float bv = BIAS_ROW ? bias[row0 + r] : bc;
        float v = (acc[mi][ni][r] + bv) * sc;
        store_out(&C[(row0 + r) * (long)N + col], v);
      }
    }
  }
}

// ---------------- flash attention v2 ----------------
// block = (b,h) x 128 q-rows; 4 waves x 32 q-rows (2 16-row frags).
// Swapped QK^T: s4 = mfma(K, Q) -> D[key][q], q = lr lane-local => scalar m/l per frag.
// PV swapped too: acc = mfma(V^T, P^T) -> O^T[d][q].
// K and V^T both staged via global_load_lds, double-buffered, pre-swizzled source.

__global__ __launch_bounds__(256) void attn_kernel(
    const unsigned short* __restrict__ QK,   // [8192][2048] bf16: cols 0..1023 Q (prescaled), 1024.. K
    const unsigned short* __restrict__ Vt,   // [1024][8192] bf16: row h*64+d, col b*2048+s
    unsigned short* __restrict__ AO) {       // [8192][1024] bf16 [b][s][h][dk]
  __shared__ unsigned short Ks[2][64 * 64];  // [key][d], 16B blocks XOR-swizzled by key&7
  __shared__ unsigned short Vs[2][64 * 64];  // [d][key], 16B blocks XOR-swizzled by d&7
  __shared__ unsigned short Pl[4][16 * 64];  // per-wave P [q16][key], 8B blocks XOR-swizzled

  const int tid = threadIdx.x;
  const int lane = tid & 63;
  const int wv = tid >> 6;
  const int lr = lane & 15, lg = lane >> 4;

  const int bh = blockIdx.x;   // x = bh so all q-tiles of one (b,h) share an XCD
  const int qt = blockIdx.y;
  const int b = bh >> 4, h = bh & 15;

  const unsigned short* Qp = QK + (long)b * SS * NQK + h * DKH;
  const unsigned short* Kp = Qp + DM;
  const unsigned short* Vp = Vt + (long)h * DKH * MROWS + (long)b * SS;

  // Q fragments (B-operand): q = frag*16 + lr, d = ks*32 + lg*8 + i
  bf16x8 qf[2][2];
#pragma unroll
  for (int f = 0; f < 2; ++f) {
    const unsigned short* qrow = Qp + (long)(qt * 128 + wv * 32 + f * 16 + lr) * NQK;
    qf[f][0] = *reinterpret_cast<const bf16x8*>(qrow + lg * 8);
    qf[f][1] = *reinterpret_cast<const bf16x8*>(qrow + 32 + lg * 8);
  }

  f32x4 acc[2][4];  // O^T: d = dblk*16 + lg*4 + r, q = frag*16 + lr
#pragma unroll
  for (int f = 0; f < 2; ++f)
#pragma unroll
    for (int d = 0; d < 4; ++d) acc[f][d] = (f32x4){0.f, 0.f, 0.f, 0.f};
  float m_run[2] = {-1e30f, -1e30f};
  float l_run[2] = {0.f, 0.f};

  unsigned short* Pw = &Pl[wv][0];

  auto stage = [&](int bf, int t) {
#pragma unroll
    for (int it = 0; it < 2; ++it) {
      const int s = it * 256 + tid;          // 16B-block index 0..511
      const int row = s >> 3, blk = s & 7;
      const int blkL = blk ^ (row & 7);      // inverse-swizzled global source (rule 21)
      gload_lds16(Kp + (long)(t * 64 + row) * NQK + (blkL << 3), &Ks[bf][s * 8]);
      gload_lds16(Vp + (long)row * MROWS + t * 64 + (blkL << 3), &Vs[bf][s * 8]);
    }
  };

  stage(0, 0);
  __syncthreads();

  const int NT = SS / 64;
  for (int kt = 0; kt < NT; ++kt) {
    const int cur = kt & 1;
    if (kt + 1 < NT) stage(cur ^ 1, kt + 1);  // prefetch next tile; latency hides under compute

    // ---- QK^T (swapped): s4[f][kb] -> S[key = kb*16+lg*4+r][q = f*16+lr] ----
    f32x4 s4[2][4];
#pragma unroll
    for (int f = 0; f < 2; ++f)
#pragma unroll
      for (int kb = 0; kb < 4; ++kb) s4[f][kb] = (f32x4){0.f, 0.f, 0.f, 0.f};
    __builtin_amdgcn_s_setprio(1);
#pragma unroll
    for (int kb = 0; kb < 4; ++kb) {
      const unsigned short* kbase = &Ks[cur][(kb * 16 + lr) * 64];
      bf16x8 kf0 = *reinterpret_cast<const bf16x8*>(kbase + ((lg ^ (lr & 7)) << 3));
      bf16x8 kf1 = *reinterpret_cast<const bf16x8*>(kbase + (((4 + lg) ^ (lr & 7)) << 3));
      s4[0][kb] = __builtin_amdgcn_mfma_f32_16x16x32_bf16(kf0, qf[0][0], s4[0][kb], 0, 0, 0);
      s4[0][kb] = __builtin_amdgcn_mfma_f32_16x16x32_bf16(kf1, qf[0][1], s4[0][kb], 0, 0, 0);
      s4[1][kb] = __builtin_amdgcn_mfma_f32_16x16x32_bf16(kf0, qf[1][0], s4[1][kb], 0, 0, 0);
      s4[1][kb] = __builtin_amdgcn_mfma_f32_16x16x32_bf16(kf1, qf[1][1], s4[1][kb], 0, 0, 0);
    }
    __builtin_amdgcn_s_setprio(0);

    // ---- online softmax, P write, pf reads (per frag; P buffer reused) ----
    bf16x8 pf[2][2];
    float scl[2];
#pragma unroll
    for (int f = 0; f < 2; ++f) {
      float mloc = s4[f][0][0];
#pragma unroll
      for (int kb = 0; kb < 4; ++kb)
#pragma unroll
        for (int r = 0; r < 4; ++r) mloc = fmaxf(mloc, s4[f][kb][r]);
      mloc = fmaxf(mloc, __shfl_xor(mloc, 16));
      mloc = fmaxf(mloc, __shfl_xor(mloc, 32));
      const float mn = fmaxf(m_run[f], mloc);
      scl[f] = __builtin_amdgcn_exp2f(m_run[f] - mn);
      m_run[f] = mn;
      float ssum = 0.f;
#pragma unroll
      for (int kb = 0; kb < 4; ++kb) {
        u16x4 pw;
#pragma unroll
        for (int r = 0; r < 4; ++r) {
          float p = __builtin_amdgcn_exp2f(s4[f][kb][r] - mn);
          ssum += p;
          pw[r] = f2bf(p);
        }
        // key-block bb = kb*4+lg (4-key/8B blocks), swizzled by even XOR of row phase
        *reinterpret_cast<u16x4*>(Pw + lr * 64 + ((((kb * 4 + lg) ^ ((lr & 7) << 1))) << 2)) = pw;
      }
      ssum += __shfl_xor(ssum, 16);
      ssum += __shfl_xor(ssum, 32);
      l_run[f] = l_run[f] * scl[f] + ssum;
      // P^T B-operand frags: row q16=lr, keys ks*32+lg*8.. (bb = ks*8+lg*2, even XOR keeps 16B pair)
      pf[f][0] = *reinterpret_cast<const bf16x8*>(Pw + lr * 64 + (((lg * 2) ^ ((lr & 7) << 1)) << 2));
      pf[f][1] = *reinterpret_cast<const bf16x8*>(Pw + lr * 64 + (((8 + lg * 2) ^ ((lr & 7) << 1)) << 2));
    }

    // ---- rescale O by exp2(m_old - m_new), scalar per frag ----
#pragma unroll
    for (int f = 0; f < 2; ++f)
#pragma unroll
      for (int d = 0; d < 4; ++d)
#pragma unroll
        for (int r = 0; r < 4; ++r) acc[f][d][r] *= scl[f];

    // ---- PV (swapped): acc[f][dblk] += mfma(V^T rows, P^T) ----
    __builtin_amdgcn_s_setprio(1);
#pragma unroll
    for (int dblk = 0; dblk < 4; ++dblk) {
      const unsigned short* vbase = &Vs[cur][(dblk * 16 + lr) * 64];
      bf16x8 vf0 = *reinterpret_cast<const bf16x8*>(vbase + ((lg ^ (lr & 7)) << 3));
      bf16x8 vf1 = *reinterpret_cast<const bf16x8*>(vbase + (((4 + lg) ^ (lr & 7)) << 3));
      acc[0][dblk] = __builtin_amdgcn_mfma_f32_16x16x32_bf16(vf0, pf[0][0], acc[0][dblk], 0, 0, 0);
      acc[0][dblk] = __builtin_amdgcn_mfma_f32_16x16x32_bf16(vf1, pf[0][1], acc[0][dblk], 0, 0, 0);
      acc[1][dblk] = __builtin_amdgcn_mfma_f32_16x16x32_bf16(vf0, pf[1][0], acc[1][dblk], 0, 0, 0);
      acc[1][dblk] = __builtin_amdgcn_mfma_f32_16x16x32_bf16(vf1, pf[1][1], acc[1][dblk], 0, 0, 0);
    }
    __builtin_amdgcn_s_setprio(0);

    __syncthreads();  // drains vmcnt for prefetch + guards buffer swap
  }

  // ---- epilogue: normalize, store bf16 [b][s][h][dk], 8B packed ----
#pragma unroll
  for (int f = 0; f < 2; ++f) {
    const float inv = 1.0f / l_run[f];
    const long row = (long)b * SS + qt * 128 + wv * 32 + f * 16 + lr;
#pragma unroll
    for (int dblk = 0; dblk < 4; ++dblk) {
      u16x4 o;
#pragma unroll
      for (int r = 0; r < 4; ++r) o[r] = f2bf(acc[f][dblk][r] * inv);
      *reinterpret_cast<u16x4*>(AO + row * DM + h * DKH + dblk * 16 + lg * 4) = o;
    }
  }
}

// ---------------- launch ----------------

extern "C" void kernel_launch(void* const* d_in, const int* in_sizes, int n_in,
                              void* d_out, int out_size, void* d_ws, size_t ws_size,
                              hipStream_t stream) {
  const float* x  = (const float*)d_in[0];
  const float* Wq = (const float*)d_in[1];
  const float* bq = (const float*)d_in[2];
  const float* Wk = (const float*)d_in[3];
  const float* bk = (const float*)d_in[4];
  const float* Wv = (const float*)d_in[5];
  const float* bv = (const float*)d_in[6];
  const float* Wo = (const float*)d_in[7];
  const float* bo = (const float*)d_in[8];
  float* out = (float*)d_out;

  char* ws = (char*)d_ws;
  size_t off = 0;
  auto alloc = [&](size_t bytes) {
    void* p = ws + off;
    off += (bytes + 255) & ~(size_t)255;
    return p;
  };
  unsigned short* Xb   = (unsigned short*)alloc((size_t)MROWS * DM * 2);   // x bf16
  unsigned short* WTqk = (unsigned short*)alloc((size_t)2 * DM * DM * 2);  // WqT,WkT stacked [2048][1024]
  unsigned short* WTv  = (unsigned short*)alloc((size_t)DM * DM * 2);      // WvT [1024][1024]
  unsigned short* WTo  = (unsigned short*)alloc((size_t)DM * DM * 2);      // WoT [1024][1024]
  float*          bqk  = (float*)alloc((size_t)NQK * 4);
  unsigned short* QKb  = (unsigned short*)alloc((size_t)MROWS * NQK * 2);  // fused QK output
  unsigned short* Vtb  = (unsigned short*)alloc((size_t)DM * MROWS * 2);   // V^T [1024][8192]
  unsigned short* AOb  = (unsigned short*)alloc((size_t)MROWS * DM * 2);   // attention output

  cvt_bf16_kernel<<<(MROWS * DM / 4 + 255) / 256, 256, 0, stream>>>(x, Xb, MROWS * DM / 4);
  transpose_cvt_kernel<<<dim3(32, 32), 256, 0, stream>>>(Wq, WTqk);
  transpose_cvt_kernel<<<dim3(32, 32), 256, 0, stream>>>(Wk, WTqk + DM * DM);
  transpose_cvt_kernel<<<dim3(32, 32), 256, 0, stream>>>(Wv, WTv);
  transpose_cvt_kernel<<<dim3(32, 32), 256, 0, stream>>>(Wo, WTo);
  concat2_bias_kernel<<<(NQK + 255) / 256, 256, 0, stream>>>(bq, bk, bqk);

  // QK projection: [8192][2048] = Xb @ WTqk^T, Q columns pre-scaled by 0.125*log2(e)
  gemm_bt_kernel<unsigned short, true, false><<<dim3(MROWS / 128, NQK / 128), 256, 0, stream>>>(
      Xb, WTqk, bqk, QKb, MROWS, NQK, DM);
  // V^T directly: Vt[feature][token] = WTv @ Xb^T + bv (bias by row)
  gemm_bt_kernel<unsigned short, false, true><<<dim3(DM / 128, MROWS / 128), 256, 0, stream>>>(
      WTv, Xb, bv, Vtb, DM, MROWS, DM);

  attn_kernel<<<dim3(BB * NH, SS / 128), 256, 0, stream>>>(QKb, Vtb, AOb);

  // output projection -> fp32 d_out
  gemm_bt_kernel<float, false, false><<<dim3(MROWS / 128, DM / 128), 256, 0, stream>>>(
      AOb, WTo, bo, out, MROWS, DM, DM);
}